// Round 5
// baseline (265.470 us; speedup 1.0000x reference)
//
#include <hip/hip_runtime.h>
#include <hip/hip_bf16.h>

// ---------------------------------------------------------------------------
// CausalCrisisLoss on MI355X.  R5: group-sorted MMD.
//  * k_prep0 (1 work block + 32 zero blocks): mask-mode detect, gid, group
//    counts, counting-sort ranks (order within group irrelevant -> sums are
//    fixed-point exact & replay-deterministic), and zeroes all accumulators
//    (replaces the hipMemsetAsync node).
//  * k_pre: cls | rowstats (scatter bf16/sq to sorted positions) + u | recon.
//  * k_big role T: sorted rows => tiles span <=2 groups/axis. Epilogue is
//    1 exp (d<200 branch for other 4; data d~512) + select-add into 4
//    register accums -> wave reduce -> <=4 global u64 atomics. No per-element
//    LDS atomics (R4: 17M ds_add + 3.7M conflict cycles). Diagonal analytic:
//    S[a][a] = 2*strictLower + 5*n_a.
//  * No float atomics anywhere (CAS-loop hazard).
// ---------------------------------------------------------------------------

typedef short bf16x8 __attribute__((ext_vector_type(8)));
typedef float f32x4 __attribute__((ext_vector_type(4)));
typedef unsigned long long u64;
typedef unsigned int u32;

static constexpr int D = 256;
static constexpr int H = 768;
static constexpr int NG = 16;
static constexpr float FX32 = 4294967296.f;
static constexpr float IFX32 = 2.3283064365386963e-10f;

__device__ inline void gAddFx(u64* p, float v) {
  long long q = (long long)llroundf(v * FX32);
  atomicAdd(p, (u64)q);                           // native global_atomic_add_x2
}
__device__ inline float fxToF(u64 v) { return (float)(long long)v * IFX32; }

__device__ inline float focal_n(const float* x, int n, int tgt,
                                float s_over_n, float oms) {
  float mx = x[0];
  for (int c = 1; c < n; ++c) mx = fmaxf(mx, x[c]);
  float se = 0.f, sx = 0.f;
  for (int c = 0; c < n; ++c) { se += __expf(x[c] - mx); sx += x[c]; }
  float logZ = mx + __logf(se);
  float ce = logZ - oms * x[tgt] - s_over_n * sx;
  float pt = __expf(x[tgt] - logZ);
  float om = 1.f - pt;
  return ce * om * om;
}

// ================================================================== k_prep0
// block 0: mode detect + gid + counts + counting-sort ranks + small zeroing
// blocks 1..32: zero U64/M64/GSP (164864 u64)
extern "C" __global__ __launch_bounds__(1024) void k_prep0(
    const void* __restrict__ mask, const int* __restrict__ y1,
    const int* __restrict__ dom,
    u64* SA, u64* GCU, int* gid, int* rank, int* gidp,
    u64* zbase, int zcount, int B) {
  int t = threadIdx.x;
  int bid = blockIdx.x;
  if (bid > 0) {
    for (int i = (bid - 1) * 1024 + t; i < zcount; i += 32 * 1024)
      zbase[i] = 0ull;
    return;
  }
  __shared__ u32 sh3[3];
  __shared__ u32 cnt[17];
  __shared__ u32 off[17];
  if (t < 3) sh3[t] = 0;
  if (t < 17) cnt[t] = 0;
  if (t < 32) SA[t] = 0ull;
  __syncthreads();
  // mode detect over first B bytes (in-bounds for u8/i32/f32)
  {
    u32 a = 0, b = 0, cd = 0;
    const unsigned char* m8 = (const unsigned char*)mask;
    for (int i = t; i < B; i += 1024) {
      u32 v = m8[i];
      int mm = i & 3;
      if (mm == 0) a |= v; else if (mm == 1) b |= v; else cd |= v;
    }
    if (a) atomicOr(&sh3[0], 1u);
    if (b) atomicOr(&sh3[1], 1u);
    if (cd) atomicOr(&sh3[2], 1u);
  }
  __syncthreads();
  int mode;
  if ((sh3[1] | sh3[2]) == 0) mode = 0;            // int32 0/1
  else if (sh3[0] == 0 && sh3[1] == 0) mode = 1;   // f32
  else mode = 2;                                   // u8
  for (int r = t; r < B; r += 1024) {
    int mi;
    if (mode == 0)      mi = ((const int*)mask)[r] ? 1 : 0;
    else if (mode == 1) mi = (((const float*)mask)[r] != 0.f) ? 1 : 0;
    else                mi = ((const unsigned char*)mask)[r] ? 1 : 0;
    int g = mi ? (y1[r] * 4 + dom[r]) : -1;
    gid[r] = g;
    atomicAdd(&cnt[g < 0 ? 16 : g], 1u);
  }
  __syncthreads();
  if (t == 0) {
    u32 s = 0;
    for (int g = 0; g < 16; ++g) { off[g] = s; s += cnt[g]; }
    off[16] = s;
    SA[5] = (u64)s;                                // msum (valid count)
  }
  __syncthreads();
  if (t < 16) GCU[t] = (u64)cnt[t];
  for (int r = t; r < B; r += 1024) {
    int g = gid[r];
    int slot = g < 0 ? 16 : g;
    int pos = (int)atomicAdd(&off[slot], 1u);
    rank[r] = pos;
    gidp[pos] = g;
  }
}

// ============================================================== k_pre (fused)
// role A [0,NA):       cls losses (validity from gid)
// role B [NA,NA+NB):   per-row norms, bf16 scatter to sorted pos, sqp, inv, u
// role C [NA+NB,+NC):  recon MSE
extern "C" __global__ __launch_bounds__(256) void k_pre(
    const int* __restrict__ y1, const int* __restrict__ dom,
    const float* __restrict__ l1, const float* __restrict__ l2,
    const float* __restrict__ l3, const int* __restrict__ y2,
    const int* __restrict__ y3,
    const float* __restrict__ vsv, const float* __restrict__ vst,
    const float* __restrict__ cv, const float* __restrict__ sv,
    const float* __restrict__ ct, const float* __restrict__ st,
    const float* __restrict__ ir, const float* __restrict__ io,
    const float* __restrict__ trc, const float* __restrict__ to,
    u64* SA, u64* U64,
    const int* __restrict__ gid, const int* __restrict__ rank,
    float* sqp, float* inv, unsigned short* bfp,
    int B, int N4, int NA, int NB) {
  __shared__ float redf[4];
  int bid = blockIdx.x;
  int t = threadIdx.x;

  if (bid < NA) {
    // ---------------- role A: cls ----------------
    int r = bid * 256 + t;
    float s[5] = {0.f, 0.f, 0.f, 0.f, 0.f};
    if (r < B && gid[r] >= 0) {
      float x[6];
      for (int c = 0; c < 4; ++c) x[c] = l1[r * 4 + c];
      s[0] = focal_n(x, 4, y1[r], 0.1f / 4.f, 0.9f);
      for (int c = 0; c < 6; ++c) x[c] = l2[r * 6 + c];
      s[1] = focal_n(x, 6, y2[r], 0.1f / 6.f, 0.9f);
      for (int c = 0; c < 3; ++c) x[c] = l3[r * 3 + c];
      s[2] = focal_n(x, 3, y3[r], 0.1f / 3.f, 0.9f);
      int d = dom[r];
      for (int c = 0; c < 4; ++c) x[c] = vsv[r * 4 + c];
      {
        float mx = fmaxf(fmaxf(x[0], x[1]), fmaxf(x[2], x[3]));
        float se = __expf(x[0]-mx)+__expf(x[1]-mx)+__expf(x[2]-mx)+__expf(x[3]-mx);
        s[3] = mx + __logf(se) - x[d];
      }
      for (int c = 0; c < 4; ++c) x[c] = vst[r * 4 + c];
      {
        float mx = fmaxf(fmaxf(x[0], x[1]), fmaxf(x[2], x[3]));
        float se = __expf(x[0]-mx)+__expf(x[1]-mx)+__expf(x[2]-mx)+__expf(x[3]-mx);
        s[4] = mx + __logf(se) - x[d];
      }
    }
    for (int k = 0; k < 5; ++k) {
      float x = s[k];
      #pragma unroll
      for (int o = 32; o > 0; o >>= 1) x += __shfl_down(x, o);
      __syncthreads();
      if ((t & 63) == 0) redf[t >> 6] = x;
      __syncthreads();
      if (t == 0) gAddFx(&SA[k], redf[0] + redf[1] + redf[2] + redf[3]);
    }
  } else if (bid < NA + NB) {
    // ---------------- role B: rowstats + scatter + u ----------------
    int b = bid - NA;
    int f = b >> 6;                          // 0..3  (cv, sv, ct, st)
    int rb = b & 63;
    const float* p = (f == 0) ? cv : (f == 1) ? sv : (f == 2) ? ct : st;
    int w = t >> 6, L = t & 63;
    float up0 = 0.f, up1 = 0.f, up2 = 0.f, up3 = 0.f;
    for (int k = 0; k < 16; ++k) {
      int r = rb * 64 + w * 16 + k;
      float4 v = ((const float4*)(p + (size_t)r * D))[L];
      float ss = v.x * v.x + v.y * v.y + v.z * v.z + v.w * v.w;
      #pragma unroll
      for (int o = 32; o > 0; o >>= 1) ss += __shfl_down(ss, o);
      ss = __shfl(ss, 0);
      float iv = 1.f / fmaxf(sqrtf(ss), 1e-12f);
      if ((f & 1) == 0) {                    // c_v / c_t -> sorted bf16 copy
        int fi = f >> 1;
        int pos = rank[r];
        alignas(8) __hip_bfloat16 hb[4];
        hb[0] = __float2bfloat16(v.x); hb[1] = __float2bfloat16(v.y);
        hb[2] = __float2bfloat16(v.z); hb[3] = __float2bfloat16(v.w);
        *(uint2*)(bfp + ((size_t)fi * B + pos) * D + L * 4) = *(uint2*)hb;
        if (L == 0) sqp[fi * B + pos] = ss;
      }
      if (L == 0) inv[f * B + r] = iv;
      up0 += v.x * iv; up1 += v.y * iv; up2 += v.z * iv; up3 += v.w * iv;
    }
    u64* Uf = U64 + f * D + 4 * L;
    gAddFx(Uf + 0, up0); gAddFx(Uf + 1, up1);
    gAddFx(Uf + 2, up2); gAddFx(Uf + 3, up3);
  } else {
    // ---------------- role C: recon ----------------
    int cidx = bid - (NA + NB);
    int j = cidx >> 8;                       // 0/1: img / txt
    int cb = cidx & 255;
    const float4* A  = (const float4*)(j ? trc : ir);
    const float4* Bp = (const float4*)(j ? to : io);
    float acc = 0.f;
    for (int idx = cb * 256 + t; idx < N4; idx += 256 * 256) {
      float4 a = A[idx], b = Bp[idx];
      float dx = a.x-b.x, dy = a.y-b.y, dz = a.z-b.z, dw = a.w-b.w;
      acc += dx*dx + dy*dy + dz*dz + dw*dw;
    }
    #pragma unroll
    for (int o = 32; o > 0; o >>= 1) acc += __shfl_down(acc, o);
    if ((t & 63) == 0) redf[t >> 6] = acc;
    __syncthreads();
    if (t == 0) gAddFx(&SA[6 + j], redf[0] + redf[1] + redf[2] + redf[3]);
  }
}

// ============================================================== k_big (fused)
// role M [0,512): M = Chat^T Shat partial GEMM
// role T [512,512+4160): sorted 64x64 Gram tiles + RBF + group-pair sums
extern "C" __global__ __launch_bounds__(256) void k_big(
    const float* __restrict__ cv, const float* __restrict__ sv,
    const float* __restrict__ ct, const float* __restrict__ st,
    const float* __restrict__ inv, u64* M64,
    const unsigned short* __restrict__ bfp, const float* __restrict__ sqp,
    const int* __restrict__ gidp, u64* GSP, int B) {
  __shared__ __align__(16) char smem[38016];
  int bid = blockIdx.x;
  int tid = threadIdx.x;

  if (bid < 512) {
    // ---------------- role M ----------------
    float (*lc)[16] = (float(*)[16])smem;         // 16 KB
    float* lis = (float*)(smem + 16384);          // 1 KB
    int p = bid >> 8;
    int a0 = ((bid >> 4) & 15) * 16;
    int i0 = (bid & 15) * 256;                    // clen = 256
    const float* c = p ? ct : cv;
    const float* s = p ? st : sv;
    const float* ic = inv + (2 * p) * B;
    const float* is = inv + (2 * p + 1) * B;
    int t = tid;
    lis[t] = is[i0 + t];
    for (int e = t; e < 256 * 16; e += 256) {
      int i = e >> 4, rr = e & 15;
      lc[i][rr] = c[(size_t)(i0 + i) * D + a0 + rr] * ic[i0 + i];
    }
    __syncthreads();
    float4 acc[4];
    #pragma unroll
    for (int r = 0; r < 4; ++r) acc[r] = make_float4(0.f, 0.f, 0.f, 0.f);
    #pragma unroll 8
    for (int i = 0; i < 256; ++i) {
      float svv = s[(size_t)(i0 + i) * D + t] * lis[i];
      const float4* lr = (const float4*)lc[i];
      #pragma unroll
      for (int r = 0; r < 4; ++r) {
        float4 c4 = lr[r];
        acc[r].x += c4.x * svv; acc[r].y += c4.y * svv;
        acc[r].z += c4.z * svv; acc[r].w += c4.w * svv;
      }
    }
    u64* Mp = M64 + (size_t)p * D * D;
    #pragma unroll
    for (int r = 0; r < 4; ++r) {
      gAddFx(&Mp[(a0 + 4 * r + 0) * D + t], acc[r].x);
      gAddFx(&Mp[(a0 + 4 * r + 1) * D + t], acc[r].y);
      gAddFx(&Mp[(a0 + 4 * r + 2) * D + t], acc[r].z);
      gAddFx(&Mp[(a0 + 4 * r + 3) * D + t], acc[r].w);
    }
    return;
  }

  // ---------------- role T: sorted mmd tile ----------------
  unsigned short* Ab = (unsigned short*)smem;               // 16 KB
  unsigned short* Bb = (unsigned short*)(smem + 16384);     // 16 KB
  u32 (*gsw)[NG * NG] = (u32(*)[NG * NG])(smem + 32768);    // 4 KB (fallback)
  int*   gA = (int*)(smem + 36864);                         // 256 B
  int*   gB = gA + 64;                                      // 256 B
  float* sA = (float*)(gB + 64);                            // 256 B
  float* sB = sA + 64;                                      // 256 B

  int idx2 = bid - 512;
  int feat = idx2 & 1;
  int tlin = idx2 >> 1;
  int NT = B / 64;
  float tf = (float)tlin;
  int ti = (int)((2.f * NT + 1.f -
                  sqrtf((2.f * NT + 1.f) * (2.f * NT + 1.f) - 8.f * tf)) * 0.5f);
  while (ti > 0 && (ti * NT - (ti * (ti - 1)) / 2) > tlin) --ti;
  while (((ti + 1) * NT - ((ti + 1) * ti) / 2) <= tlin) ++ti;
  int tj = ti + (tlin - (ti * NT - (ti * (ti - 1)) / 2));
  int i0 = ti * 64, j0 = tj * 64;
  bool diag = (ti == tj);
  const unsigned short* fb = bfp + (size_t)feat * B * D;
  const float* sqf = sqp + (size_t)feat * B;

  int w = tid >> 6, L = tid & 63, m = L & 15, q = L >> 4;

  { // prologue (pre-barrier): zero fallback hist, cache tile gid/sq
    u32* gz = (u32*)gsw;
    #pragma unroll
    for (int e = 0; e < 4; ++e) gz[tid + 256 * e] = 0;
    if (tid < 64) { gA[tid] = gidp[i0 + tid]; sA[tid] = sqf[i0 + tid]; }
    else if (tid < 128) { int r = tid - 64; gB[r] = gidp[j0 + r]; sB[r] = sqf[j0 + r]; }
  }

  f32x4 acc[4] = {{0.f,0.f,0.f,0.f},{0.f,0.f,0.f,0.f},{0.f,0.f,0.f,0.f},{0.f,0.f,0.f,0.f}};

  for (int h = 0; h < 2; ++h) {              // K halves of 128
    if (h) __syncthreads();
    for (int e = tid; e < 1024; e += 256) {
      int row = e >> 4, ck = e & 15;
      uint4 v = *(const uint4*)(fb + (size_t)(i0 + row) * D + h * 128 + ck * 8);
      *(uint4*)&Ab[row * 128 + ((ck ^ (row & 15)) * 8)] = v;
    }
    if (!diag) {
      for (int e = tid; e < 1024; e += 256) {
        int row = e >> 4, ck = e & 15;
        uint4 v = *(const uint4*)(fb + (size_t)(j0 + row) * D + h * 128 + ck * 8);
        *(uint4*)&Bb[row * 128 + ((ck ^ (row & 15)) * 8)] = v;
      }
    }
    __syncthreads();
    const unsigned short* Bp = diag ? Ab : Bb;
    #pragma unroll
    for (int kk = 0; kk < 4; ++kk) {
      int ar = w * 16 + m;
      bf16x8 aF = *(const bf16x8*)&Ab[ar * 128 + (((kk * 4 + q) ^ (ar & 15)) * 8)];
      #pragma unroll
      for (int c = 0; c < 4; ++c) {
        int br = c * 16 + m;
        bf16x8 bF = *(const bf16x8*)&Bp[br * 128 + (((kk * 4 + q) ^ (br & 15)) * 8)];
        acc[c] = __builtin_amdgcn_mfma_f32_16x16x32_bf16(aF, bF, acc[c], 0, 0, 0);
      }
    }
  }
  // ---- epilogue: sorted groups => <=2 groups/axis typical.
  // C/D layout (m89/m91): col = lane&15, row = (lane>>4)*4 + reg.
  int ga0 = gA[0], ga1 = gA[63], gb0 = gB[0], gb1 = gB[63];
  int ri0 = w * 16 + q * 4;
  int giv[4] = {gA[ri0], gA[ri0 + 1], gA[ri0 + 2], gA[ri0 + 3]};
  float siv[4] = {sA[ri0], sA[ri0 + 1], sA[ri0 + 2], sA[ri0 + 3]};
  float a00 = 0.f, a01 = 0.f, a10 = 0.f, a11 = 0.f;
  #pragma unroll
  for (int c = 0; c < 4; ++c) {
    int rj = c * 16 + m;
    int gj = gB[rj];
    float sb = sB[rj];
    #pragma unroll
    for (int v = 0; v < 4; ++v) {
      int ri = ri0 + v;
      int gi = giv[v];
      bool on = (gi >= 0) && (gj >= 0) && (!diag || (ri < rj));
      if (on) {
        float d = fmaxf(siv[v] + sb - 2.f * acc[c][v], 0.f);
        float K = __expf(-0.01f * d);
        if (d < 200.f)                        // data: d ~ 512; ~never taken
          K += __expf(-0.1f * d) + __expf(-d) + __expf(-10.f * d)
             + __expf(-100.f * d);
        int si_ = (gi == ga0) ? 0 : ((gi == ga1) ? 2 : -4);
        int sj_ = (gj == gb0) ? 0 : ((gj == gb1) ? 1 : -4);
        if (si_ >= 0 && sj_ >= 0) {
          int sel = si_ + sj_;
          a00 += (sel == 0) ? K : 0.f;
          a01 += (sel == 1) ? K : 0.f;
          a10 += (sel == 2) ? K : 0.f;
          a11 += (sel == 3) ? K : 0.f;
        } else {                              // >2 groups per axis (rare)
          atomicAdd(&gsw[w][gi * NG + gj], (u32)(K * 65536.f + 0.5f));
        }
      }
    }
  }
  // wave reduce 4 accums (deterministic shfl tree), then <=4 global atomics
  #pragma unroll
  for (int o = 32; o > 0; o >>= 1) {
    a00 += __shfl_down(a00, o); a01 += __shfl_down(a01, o);
    a10 += __shfl_down(a10, o); a11 += __shfl_down(a11, o);
  }
  u64* gbase = GSP + ((size_t)(tlin & 63) * 2 + feat) * NG * NG;
  if (L == 0) {
    float vals[4] = {a00, a01, a10, a11};
    int gx[4] = {ga0, ga0, ga1, ga1};
    int gy[4] = {gb0, gb1, gb0, gb1};
    #pragma unroll
    for (int k = 0; k < 4; ++k) {
      if (vals[k] != 0.f) {
        int x = min(gx[k], gy[k]), y = max(gx[k], gy[k]);
        atomicAdd(&gbase[x * NG + y], (u64)(vals[k] * 65536.f + 0.5f));
      }
    }
  }
  __syncthreads();
  if (tid < NG * NG) {                        // flush fallback hist
    u64 s = (u64)gsw[0][tid] + gsw[1][tid] + gsw[2][tid] + gsw[3][tid];
    if (s) atomicAdd(&gbase[tid], s);
  }
}

// ----------------------------------------- hsic partials: tr(KL), u^T M v
extern "C" __global__ __launch_bounds__(256) void k_hsic(
    const u64* __restrict__ U64, const u64* __restrict__ M64, u64* SA) {
  __shared__ float red[8];
  __shared__ float ush[32], vsh[D];
  int p = blockIdx.y;
  int k0 = blockIdx.x * 32;
  int t = threadIdx.x;
  vsh[t] = fxToF(U64[(2 * p + 1) * D + t]);
  if (t < 32) ush[t] = fxToF(U64[(2 * p) * D + k0 + t]);
  __syncthreads();
  const u64* Mp = M64 + (size_t)p * D * D;
  float trkl = 0.f, cr = 0.f;
  #pragma unroll 4
  for (int k = 0; k < 32; ++k) {
    float mv = fxToF(Mp[(size_t)(k0 + k) * D + t]);
    trkl += mv * mv;
    cr += ush[k] * mv;
  }
  cr *= vsh[t];
  #pragma unroll
  for (int o = 32; o > 0; o >>= 1) { trkl += __shfl_down(trkl, o); cr += __shfl_down(cr, o); }
  if ((t & 63) == 0) { red[t >> 6] = trkl; red[4 + (t >> 6)] = cr; }
  __syncthreads();
  if (t == 0) gAddFx(&SA[10 + p], red[0] + red[1] + red[2] + red[3]);
  if (t == 64) gAddFx(&SA[12 + p], red[4] + red[5] + red[6] + red[7]);
}

// ----------------------------------------------------------------- finalize
extern "C" __global__ __launch_bounds__(256) void k_final(
    const u64* SA, const u64* GCU, const u64* GSP,
    const u64* U64, float* out, int B) {
  __shared__ float red[8];
  __shared__ float gssh[2 * NG * NG];
  int t = threadIdx.x;
  for (int e = t; e < 2 * NG * NG; e += 256) {
    u64 ssum = 0;
    int f = e >> 8, idx = e & 255;
    for (int cpy = 0; cpy < 64; ++cpy)
      ssum += GSP[((size_t)cpy * 2 + f) * NG * NG + idx];
    gssh[e] = (float)((double)ssum * (1.0 / 65536.0));
  }
  __syncthreads();

  float n = (float)B;
  float hs[2];
  for (int p = 0; p < 2; ++p) {
    float ut = fxToF(U64[(2 * p) * D + t]);
    float vt = fxToF(U64[(2 * p + 1) * D + t]);
    float uu = ut * ut, vv = vt * vt;
    #pragma unroll
    for (int o = 32; o > 0; o >>= 1) { uu += __shfl_down(uu, o); vv += __shfl_down(vv, o); }
    __syncthreads();
    if ((t & 63) == 0) { red[t >> 6] = uu; red[4 + (t >> 6)] = vv; }
    __syncthreads();
    float uus = red[0] + red[1] + red[2] + red[3];
    float vvs = red[4] + red[5] + red[6] + red[7];
    float trkl = (float)((double)(long long)SA[10 + p] * (double)IFX32);
    float cr   = (float)((double)(long long)SA[12 + p] * (double)IFX32);
    hs[p] = (trkl - (2.f / n) * cr + uus * vvs / (n * n))
          / ((n - 1.f) * (n - 1.f));
    __syncthreads();
  }
  if (t == 0) {
    float msum = fmaxf((float)SA[5], 1.f);
    float f1 = fxToF(SA[0]) / msum;
    float f2 = fxToF(SA[1]) / msum;
    float f3 = fxToF(SA[2]) / msum;
    float cesv = fxToF(SA[3]) / msum;
    float cest = fxToF(SA[4]) / msum;
    float mmd[2];
    for (int f = 0; f < 2; ++f) {
      float loss = 0.f, cntv = 0.f;
      for (int lab = 0; lab < 4; ++lab)
        for (int d1 = 0; d1 < 4; ++d1)
          for (int d2 = d1 + 1; d2 < 4; ++d2) {
            int a = lab * 4 + d1, b = lab * 4 + d2;
            float n1 = (float)GCU[a], n2 = (float)GCU[b];
            if (n1 > 1.f && n2 > 1.f) {
              // bins are strict-lower sums: S[a][a] = 2*bin + 5*n_a
              float g11 = 2.f * gssh[f * 256 + a * NG + a] + 5.f * n1;
              float g22 = 2.f * gssh[f * 256 + b * NG + b] + 5.f * n2;
              float g12 = gssh[f * 256 + a * NG + b];
              loss += g11 / (fmaxf(n1, 1.f) * fmaxf(n1, 1.f))
                    + g22 / (fmaxf(n2, 1.f) * fmaxf(n2, 1.f))
                    - 2.f * g12 / fmaxf(n1 * n2, 1.f);
              cntv += 1.f;
            }
          }
      mmd[f] = loss / fmaxf(cntv, 1.f);
    }
    double rs = ((double)(long long)SA[6] + (double)(long long)SA[7])
              * (double)IFX32;
    float recon = (float)(rs / ((double)B * (double)H));
    float total = 0.4f * f1 + 0.3f * f2 + 0.3f * f3
                + 0.1f * (cesv + cest + mmd[0] + mmd[1])
                + 0.1f * (hs[0] + hs[1])
                + recon;
    out[0] = total;
  }
}

// ---------------------------------------------------------------------------
extern "C" void kernel_launch(void* const* d_in, const int* in_sizes, int n_in,
                              void* d_out, int out_size, void* d_ws, size_t ws_size,
                              hipStream_t stream) {
  const float* l1  = (const float*)d_in[0];
  const int*   y1  = (const int*)d_in[1];
  const float* l2  = (const float*)d_in[2];
  const int*   y2  = (const int*)d_in[3];
  const float* l3  = (const float*)d_in[4];
  const int*   y3  = (const int*)d_in[5];
  const float* cv  = (const float*)d_in[6];
  const float* sv  = (const float*)d_in[7];
  const float* ct  = (const float*)d_in[8];
  const float* st  = (const float*)d_in[9];
  const float* vsv = (const float*)d_in[10];
  const float* vst = (const float*)d_in[11];
  const int*   dom = (const int*)d_in[12];
  const void*  mask= d_in[13];
  const float* ir  = (const float*)d_in[14];
  const float* io  = (const float*)d_in[15];
  const float* trc = (const float*)d_in[16];
  const float* to  = (const float*)d_in[17];
  int B = in_sizes[1];                        // 4096

  u64* SA  = (u64*)d_ws;                      // 32
  u64* GCU = SA + 32;                         // 16
  u64* U64 = GCU + 16;                        // 4*256
  u64* M64 = U64 + 4 * D;                     // 2*256*256
  u64* GSP = M64 + 2 * D * D;                 // 64*2*256
  u64* zend = GSP + 64 * 2 * NG * NG;
  int zcount = (int)(zend - U64);             // u64s zeroed by k_prep0
  int*   gid  = (int*)zend;                   // B
  int*   rank = gid + B;                      // B
  int*   gidp = rank + B;                     // B
  float* sqp  = (float*)(gidp + B);           // 2*B
  float* inv  = sqp + 2 * B;                  // 4*B
  unsigned short* bfp = (unsigned short*)(inv + 4 * B); // 2*B*D bf16 (sorted)

  int NA = B / 256;                           // 16
  int NB = 4 * (B / 64);                      // 256
  int NC = 512;
  int N4 = B * H / 4;

  k_prep0<<<33, 1024, 0, stream>>>(mask, y1, dom, SA, GCU, gid, rank, gidp,
                                   U64, zcount, B);
  k_pre<<<NA + NB + NC, 256, 0, stream>>>(
      y1, dom, l1, l2, l3, y2, y3, vsv, vst,
      cv, sv, ct, st, ir, io, trc, to,
      SA, U64, gid, rank, sqp, inv, bfp, B, N4, NA, NB);
  int NT = B / 64;
  int nmmd = 2 * (NT * (NT + 1) / 2);
  k_big<<<512 + nmmd, 256, 0, stream>>>(cv, sv, ct, st, inv, M64,
                                        bfp, sqp, gidp, GSP, B);
  k_hsic<<<dim3(8, 2), 256, 0, stream>>>(U64, M64, SA);
  k_final<<<1, 256, 0, stream>>>(SA, GCU, GSP, U64, (float*)d_out, B);
}